// Round 2
// baseline (456.241 us; speedup 1.0000x reference)
//
#include <hip/hip_runtime.h>

typedef unsigned short u16;
typedef __attribute__((ext_vector_type(8))) short short8;
typedef __attribute__((ext_vector_type(4))) short short4_t;
typedef __attribute__((ext_vector_type(4))) float floatx4;

#define MFMA16(A, B, C) __builtin_amdgcn_mfma_f32_16x16x32_bf16((A), (B), (C), 0, 0, 0)

// ws layout (u16 element offsets)
#define OF_SPEC  64                       // canonical bf16 spec [204800]
#define OF_SMALL (OF_SPEC + 204800)       // W1(0) b1(256) fq(512) fk(768) fv(1024)
#define OF_PART  (OF_SMALL + 1536)        // 8x256 f32 partials for fused bp (4096 u16)
#define OF_FW    (OF_PART + 4096)         // fused weights frag-major: Wq' Wk' Wv' (3x65536) + Wp'(524288)

static __device__ __forceinline__ float bf2f(u16 u) {
  union { unsigned int i; float f; } z; z.i = ((unsigned int)u) << 16; return z.f;
}
static __device__ __forceinline__ u16 f2bf(float f) {
  union { float f; unsigned int i; } z; z.f = f;
  unsigned int x = z.i + 0x7fffu + ((z.i >> 16) & 1u);  // RNE
  return (u16)(x >> 16);
}
static __device__ __forceinline__ void ld8f(const u16* p, float* o) {
  union { short8 v; u16 u[8]; } t;
  t.v = *(const short8*)p;
#pragma unroll
  for (int j = 0; j < 8; ++j) o[j] = bf2f(t.u[j]);
}

// bf16 (0) vs f32 (1) input detection on first 256 u16 of spec; per-wave ballot,
// every wave computes the same value (no separate kernel / flag memory needed).
static __device__ __forceinline__ int detect_flag(const u16* __restrict__ sp) {
  const int lane = threadIdx.x & 63;
  int bad = 0;
#pragma unroll
  for (int j = 0; j < 4; ++j) {
    u16 v = sp[lane * 4 + j];
    int e = (v >> 7) & 0xFF;
    bad += (e >= 137);
  }
  return (__popcll(__ballot(bad > 0)) >= 4) ? 1 : 0;
}

#define CV(src, idx) (flag ? f2bf(((const float*)(src))[idx]) : ((const u16*)(src))[idx])

// One launch: canonicalize (blocks 0..801), weight folds (802..977),
// bias folds (978..988).
//   g=0..2:  Wg' = W2 @ {Wq,Wk,Wv}       (q = relu(s*W1+b1) @ Wg' + fg)
//   g=3..10: Wp'_p = Wo @ Wp[p*256:...]   (patch = sum_p o_raw_p @ Wp'_p + fb)
// Folded weights written bf16 fragment-major: dst[(k>>3)*2048 + n*8 + (k&7)].
__global__ void prep_kernel(
    const void* spec, const void* W1, const void* b1, const void* W2, const void* b2,
    const void* Wq, const void* bq, const void* Wk, const void* bk, const void* Wv,
    const void* bv_, const void* Wo, const void* bo, const void* Wp, const void* bp,
    u16* __restrict__ ws) {
  const int flag = detect_flag((const u16*)spec);
  const int b = blockIdx.x;
  if (b < 802) {
    int i = b * 256 + threadIdx.x;
    if (i < 204800) { ws[OF_SPEC + i] = CV(spec, i); return; }
    int j = i - 204800;
    if (j < 256) ws[OF_SMALL + j] = CV(W1, j);
    else         ws[OF_SMALL + j] = CV(b1, j - 256);
    return;
  }
  const int f = b - 802;
  if (f >= 176) {
    const int t = f - 176;
    const int n = threadIdx.x;
    if (t < 3) {
      const void* SB = (t == 0) ? Wq : (t == 1) ? Wk : Wv;
      const void* bs = (t == 0) ? bq : (t == 1) ? bk : bv_;
      float acc = bf2f(CV(bs, n));
      for (int k = 0; k < 256; ++k)
        acc = fmaf(bf2f(CV(b2, k)), bf2f(CV(SB, k * 256 + n)), acc);
      ws[OF_SMALL + 512 + t * 256 + n] = f2bf(acc);
    } else {
      const int p = t - 3;
      float acc = 0.f;
      for (int m = 0; m < 256; ++m)
        acc = fmaf(bf2f(CV(bo, m)), bf2f(CV(Wp, (p * 256 + m) * 256 + n)), acc);
      ((float*)(ws + OF_PART))[p * 256 + n] = acc;
    }
    return;
  }
  const int g = f >> 4, sub = f & 15;
  const int r0 = (sub >> 2) * 64, c0 = (sub & 3) * 64;
  const void* SA = (g < 3) ? W2 : Wo;
  const void* SB = (g == 0) ? Wq : (g == 1) ? Wk : (g == 2) ? Wv : Wp;
  const int brow0 = (g < 3) ? 0 : (g - 3) * 256;   // also the output-k offset for Wp'
  const int tid = threadIdx.x;
  const int w = tid >> 6, lane = tid & 63, l15 = lane & 15, quad = lane >> 4;
  const int arow = r0 + w * 16 + l15;
  floatx4 acc[4];
#pragma unroll
  for (int ni = 0; ni < 4; ++ni) acc[ni] = (floatx4){0.f, 0.f, 0.f, 0.f};
  for (int kc = 0; kc < 8; ++kc) {
    const int k0 = kc * 32 + quad * 8;
    union { short8 s8; u16 u[8]; } av;
#pragma unroll
    for (int j = 0; j < 8; ++j) av.u[j] = CV(SA, arow * 256 + k0 + j);
#pragma unroll
    for (int ni = 0; ni < 4; ++ni) {
      const int colx = c0 + ni * 16 + l15;
      union { short8 s8; u16 u[8]; } bu;
#pragma unroll
      for (int j = 0; j < 8; ++j) bu.u[j] = CV(SB, (brow0 + k0 + j) * 256 + colx);
      acc[ni] = MFMA16(av.s8, bu.s8, acc[ni]);
    }
  }
  u16* dst = ws + OF_FW + ((g < 3) ? g * 65536 : 3 * 65536);
#pragma unroll
  for (int ni = 0; ni < 4; ++ni) {
    const int n = c0 + ni * 16 + l15;
#pragma unroll
    for (int r = 0; r < 4; ++r) {
      const int k = brow0 + r0 + w * 16 + quad * 4 + r;
      dst[(k >> 3) * 2048 + n * 8 + (k & 7)] = f2bf(acc[ni][r]);
    }
  }
}

// One block = 64 tokens = 8 windows, fully fused. W2 folded into Wq/Wk/Wv,
// Wo folded into Wp. Attention (QK^T, softmax, PV) runs on the matrix pipe:
// window-pairs packed block-diagonally into 16x16x32 MFMAs.
__global__ __launch_bounds__(256, 2) void fused_kernel(
    const u16* __restrict__ spec_raw,
    const u16* __restrict__ csp, const u16* __restrict__ csm,
    const u16* __restrict__ sWq, const u16* __restrict__ sWk,
    const u16* __restrict__ sWv, const u16* __restrict__ sWp,
    const void* __restrict__ bp, const float* __restrict__ part,
    void* __restrict__ out)
{
  __shared__ u16 lds[28672];          // 57344 B -> 2 blocks/CU
  u16* aA  = lds;                     // 16384: frag-major a[m<64][k<256]; later patchA
  u16* qb  = lds + 16384;             // 64 x 64, XOR-swizzled cols (+ wave-local P scratch)
  u16* kb  = qb + 4096;
  u16* vbT = kb + 4096;               // 64 cols x 64 rows (transposed V), swizzled tok-blocks

  const u16* cW1 = csm;
  const u16* cb1 = csm + 256;
  const u16* cfq = csm + 512;
  const u16* cfk = csm + 768;
  const u16* cfv = csm + 1024;

  const int flag = detect_flag(spec_raw);
  const int tid = threadIdx.x;
  const int wave = tid >> 6, lane = tid & 63;
  const int l15 = lane & 15, quad = lane >> 4;
  const int tile0 = blockIdx.x * 64;
  const floatx4 zero4 = (floatx4){0.f, 0.f, 0.f, 0.f};

  // ---------------- a-fill: relu(s*W1+b1) -> aA fragment-major ----------------
  {
    const int m = tid & 63;
    const int k8base = (tid >> 6) * 8;
    const float s = bf2f(csp[tile0 + m]);
#pragma unroll
    for (int c = 0; c < 8; ++c) {
      const int k8 = k8base + c;
      float w1f[8], b1f[8];
      ld8f(cW1 + k8 * 8, w1f);
      ld8f(cb1 + k8 * 8, b1f);
      union { short8 s8; u16 u[8]; } t;
#pragma unroll
      for (int j = 0; j < 8; ++j) {
        float x = fmaf(s, w1f[j], b1f[j]);
        t.u[j] = f2bf(x > 0.f ? x : 0.f);
      }
      *(short8*)(aA + k8 * 512 + m * 8) = t.s8;
    }
  }
  __syncthreads();

  unsigned opk[32];                   // packed bf16 attention outputs (2 per PV MFMA)

  // ---------------- 4 chunks of 2 heads (64 cols) each ------------------
#pragma unroll
  for (int c = 0; c < 4; ++c) {
    const int nb_c = c * 64;
    const int col = nb_c + wave * 16 + l15;

    // q,k,v GEMMs (fused weights: K=256 over a)
    {
      floatx4 facc[3][4];
#pragma unroll
      for (int x = 0; x < 3; ++x)
#pragma unroll
        for (int mi = 0; mi < 4; ++mi) facc[x][mi] = zero4;
      for (int kc = 0; kc < 8; ++kc) {
        short8 afr[4];
#pragma unroll
        for (int mi = 0; mi < 4; ++mi)
          afr[mi] = *(const short8*)(aA + (kc * 4 + quad) * 512 + (mi * 16 + l15) * 8);
        const int wo = ((kc * 4 + quad) * 256 + col) * 8;
        short8 bq8 = *(const short8*)(sWq + wo);
        short8 bk8 = *(const short8*)(sWk + wo);
        short8 bv8 = *(const short8*)(sWv + wo);
#pragma unroll
        for (int mi = 0; mi < 4; ++mi) {
          facc[0][mi] = MFMA16(afr[mi], bq8, facc[0][mi]);
          facc[1][mi] = MFMA16(afr[mi], bk8, facc[1][mi]);
          facc[2][mi] = MFMA16(afr[mi], bv8, facc[2][mi]);
        }
      }
      const int lc = wave * 16 + l15;
      const float bqv = bf2f(cfq[col]), bkv = bf2f(cfk[col]), bvv = bf2f(cfv[col]);
#pragma unroll
      for (int mi = 0; mi < 4; ++mi) {
#pragma unroll
        for (int r = 0; r < 4; ++r) {
          const int tr = mi * 16 + quad * 4 + r;
          const int rr = tr * 64 + ((((lc >> 3) ^ (tr & 7)) << 3) | (lc & 7));
          qb[rr] = f2bf(facc[0][mi][r] + bqv);
          kb[rr] = f2bf(facc[1][mi][r] + bkv);
        }
        // transposed V: vbT[col][tr] at col*64 + ((tr>>3 ^ col&7)<<3) + (tr&7)
        union { short4_t s4; u16 u[4]; } tv;
#pragma unroll
        for (int r = 0; r < 4; ++r) tv.u[r] = f2bf(facc[2][mi][r] + bvv);
        *(short4_t*)(vbT + lc * 64 + (((mi * 2 + (quad >> 1)) ^ (lc & 7)) << 3) +
                     (quad & 1) * 4) = tv.s4;
      }
    }
    __syncthreads();

    // ---- MFMA attention: wave w owns windows {2w, 2w+1}, both heads ----
    // Scores: A rows / B cols = 16 tokens of the window pair; diag 8x8 blocks
    // valid. Softmax: shfl reduce over 8 k-lanes. P repacked block-diagonally
    // into a wave-local scratch (aliases this wave's own Q rows - Q reads for
    // both heads complete first). PV: K slots 0..15 = both windows, 16..31 = 0.
    {
      const int w2 = wave * 2;
      const int rq = (wave * 16 + l15) * 64;
      u16* pscr = qb + wave * 1024;
      const int validk = ((l15 >> 3) == (quad >> 1));

      floatx4 sc2[2];
#pragma unroll
      for (int hl = 0; hl < 2; ++hl) {
        const int c8s = (((hl * 4 + quad) ^ (l15 & 7)) << 3);
        short8 qf = *(const short8*)(qb + rq + c8s);
        short8 kf = *(const short8*)(kb + rq + c8s);
        sc2[hl] = MFMA16(qf, kf, zero4);
      }
      u16 pb[2][4];
#pragma unroll
      for (int hl = 0; hl < 2; ++hl) {
#pragma unroll
        for (int r = 0; r < 4; ++r) {
          float s = sc2[hl][r] * 0.17677669529663687f;   // 1/sqrt(32)
          float mx = fmaxf(s, __shfl_xor(s, 1));
          mx = fmaxf(mx, __shfl_xor(mx, 2));
          mx = fmaxf(mx, __shfl_xor(mx, 4));
          float p = __expf(s - mx);
          float sum = p + __shfl_xor(p, 1);
          sum += __shfl_xor(sum, 2);
          sum += __shfl_xor(sum, 4);
          pb[hl][r] = f2bf(validk ? p / sum : 0.f);
        }
      }
#pragma unroll
      for (int hl = 0; hl < 2; ++hl)
#pragma unroll
        for (int r = 0; r < 4; ++r)
          pscr[hl * 256 + (quad * 4 + r) * 16 + l15] = pb[hl][r];

#pragma unroll
      for (int hl = 0; hl < 2; ++hl) {
#pragma unroll
        for (int dh = 0; dh < 2; ++dh) {
          const int vcol = hl * 32 + dh * 16 + l15;
          short8 pa = (short8){0, 0, 0, 0, 0, 0, 0, 0};
          short8 vf = (short8){0, 0, 0, 0, 0, 0, 0, 0};
          if (quad < 2) {
            pa = *(const short8*)(pscr + hl * 256 + l15 * 16 + quad * 8);
            vf = *(const short8*)(vbT + vcol * 64 + (((w2 + quad) ^ (vcol & 7)) << 3));
          }
          floatx4 o = MFMA16(pa, vf, zero4);
          const int oi = ((c * 2 + hl) * 2 + dh) * 2;
          opk[oi]     = (unsigned)f2bf(o[0]) | ((unsigned)f2bf(o[1]) << 16);
          opk[oi + 1] = (unsigned)f2bf(o[2]) | ((unsigned)f2bf(o[3]) << 16);
        }
      }
    }
    if (c < 3) __syncthreads();
  }

  // attention outputs -> patchA (reusing aA region), frag-major over k in
  // [0,2048): k = p*256 + D, addr = (p*32 + (D>>3))*64 + win*8 + (D&7).
  // Per PV MFMA: win = 2*wave + (quad>>1), p = (quad&1)*4 + r, D-block = 2*i16.
  {
    const int abase = (2 * wave + (quad >> 1)) * 8 + (l15 & 7) + ((l15 >> 3) << 6);
    const int pb4 = (quad & 1) * 4;
#pragma unroll
    for (int i16 = 0; i16 < 16; ++i16) {
      const unsigned lo = opk[i16 * 2], hi = opk[i16 * 2 + 1];
      u16* q0 = aA + abase + i16 * 128 + pb4 * 2048;
      q0[0]        = (u16)lo;
      q0[2048]     = (u16)(lo >> 16);
      q0[2 * 2048] = (u16)hi;
      q0[3 * 2048] = (u16)(hi >> 16);
    }
  }
  __syncthreads();

  // ---------------- patch projection: [8 x 2048] @ Wp' + fb ----------------
  // A-frag lanes 8..15 broadcast rows 0..7 (same address, free); their output
  // rows are discarded. fb = bp + sum of the 8 bo@Wp_p partials (f32).
  {
    const int w8 = (l15 & 7) * 8;
    floatx4 pacc[4];
#pragma unroll
    for (int ni = 0; ni < 4; ++ni) pacc[ni] = zero4;
#pragma unroll 4
    for (int kc = 0; kc < 64; ++kc) {
      short8 afr = *(const short8*)(aA + (kc * 4 + quad) * 64 + w8);
#pragma unroll
      for (int ni = 0; ni < 4; ++ni) {
        const int n = wave * 64 + ni * 16 + l15;
        short8 bfr = *(const short8*)(sWp + ((kc * 4 + quad) * 256 + n) * 8);
        pacc[ni] = MFMA16(afr, bfr, pacc[ni]);
      }
    }
    if (quad < 2) {
#pragma unroll
      for (int ni = 0; ni < 4; ++ni) {
        const int n = wave * 64 + ni * 16 + l15;
        float bb = bf2f(CV(bp, n));
#pragma unroll
        for (int p = 0; p < 8; ++p) bb += part[p * 256 + n];
        if (flag) {
          float* po = (float*)out;
#pragma unroll
          for (int r = 0; r < 4; ++r)
            po[(blockIdx.x * 8 + quad * 4 + r) * 256 + n] = pacc[ni][r] + bb;
        } else {
          u16* po = (u16*)out;
#pragma unroll
          for (int r = 0; r < 4; ++r)
            po[(blockIdx.x * 8 + quad * 4 + r) * 256 + n] = f2bf(pacc[ni][r] + bb);
        }
      }
    }
  }
}

extern "C" void kernel_launch(void* const* d_in, const int* in_sizes, int n_in,
                              void* d_out, int out_size, void* d_ws, size_t ws_size,
                              hipStream_t stream) {
  (void)in_sizes; (void)n_in; (void)out_size; (void)ws_size;
  u16* ws = (u16*)d_ws;

  prep_kernel<<<989, 256, 0, stream>>>(
      d_in[0], d_in[1], d_in[2], d_in[3], d_in[4], d_in[5], d_in[6], d_in[7],
      d_in[8], d_in[9], d_in[10], d_in[11], d_in[12], d_in[13], d_in[14], ws);
  fused_kernel<<<3200, 256, 0, stream>>>(
      (const u16*)d_in[0],
      ws + OF_SPEC, ws + OF_SMALL,
      ws + OF_FW, ws + OF_FW + 65536, ws + OF_FW + 2 * 65536, ws + OF_FW + 3 * 65536,
      d_in[14], (const float*)(ws + OF_PART),
      d_out);
}